// Round 3
// baseline (727.735 us; speedup 1.0000x reference)
//
#include <hip/hip_runtime.h>
#include <hip/hip_bf16.h>

// BayesianKAN: 3 layers of  out[b,o] = sum_{i,k} B-spline-basis(x[b,i])[k] * cm[o,i,k]
// == GEMM (M=8192, N=OUT, K=IN*16) with generated A-operand, plus KL scalar.
// Numerics: split-bf16 3-term MFMA for layers 0/1 (downstream noise gain ~130x),
// plain bf16 for layer 2. Validated R1/R2: absmax 0.0625 vs threshold ~0.19.
// R3: occupancy rewrite. R2 showed MfmaUtil 35% ~= VALUBusy (VALU is the MFMAs
// themselves) with Occupancy 22.5% -> stall-bound at 2 blocks/CU (LDS 69632).
// New shape: tile 64x128, BK=32 -> LDS 26624, acc 32 regs/thread, grid 1024.

typedef __attribute__((ext_vector_type(8))) short short8;   // 8 bf16 in 4 VGPRs
typedef __attribute__((ext_vector_type(4))) float float4v;  // MFMA accumulator
typedef unsigned short ushort_t;

__device__ __forceinline__ ushort_t f2bf(float f) {
  unsigned u = __float_as_uint(f);
  u += 0x7fffu + ((u >> 16) & 1u);          // round-to-nearest-even
  return (ushort_t)(u >> 16);
}
__device__ __forceinline__ float bf2f(ushort_t h) {
  return __uint_as_float(((unsigned)h) << 16);
}

// Cubic B-spline (n_basis=16, clamped uniform knots: 13 cells of width 1/13).
__device__ __forceinline__ void bspline_w4(float x, int& k0, float w[4]) {
  const float XMAX = 1.0f - 1e-6f;
  float xe = fminf(fmaxf(x, 0.0f), XMAX);
  int cell = (int)(xe * 13.0f);
  cell = cell > 12 ? 12 : cell;
  k0 = cell;
  int j = cell + 3;                 // knot span, 3..15
  const float s = 1.0f / 13.0f;
  int cjm2 = max(j - 5, 0);
  int cjm1 = max(j - 4, 0);
  int cj   = j - 3;
  int cj1  = j - 2;
  int cj2  = min(j - 1, 13);
  int cj3  = min(j, 13);
  float tjm2 = cjm2 * s, tjm1 = cjm1 * s, tj = cj * s;
  float tj1 = cj1 * s, tj2 = cj2 * s, tj3 = cj3 * s;
  float left1 = xe - tj, left2 = xe - tjm1, left3 = xe - tjm2;
  float right1 = tj1 - xe, right2 = tj2 - xe, right3 = tj3 - xe;
#define INV3(d) ((d) == 1 ? 13.0f : ((d) == 2 ? 6.5f : (13.0f / 3.0f)))
  float i10 = INV3(cj1 - cj);
  float i20 = INV3(cj1 - cjm1), i21 = INV3(cj2 - cj);
  float i30 = INV3(cj1 - cjm2), i31 = INV3(cj2 - cjm1), i32 = INV3(cj3 - cj);
#undef INV3
  float temp = i10;
  float N0 = right1 * temp;
  float N1 = left1 * temp;
  temp = N0 * i20;
  N0 = right1 * temp;
  float saved = left2 * temp;
  temp = N1 * i21;
  N1 = saved + right2 * temp;
  float N2 = left1 * temp;
  temp = N0 * i30;
  N0 = right1 * temp;
  saved = left3 * temp;
  temp = N1 * i31;
  N1 = saved + right2 * temp;
  saved = left2 * temp;
  temp = N2 * i32;
  N2 = saved + right3 * temp;
  float N3 = left1 * temp;
  w[0] = N0; w[1] = N1; w[2] = N2; w[3] = N3;
}

// Fused basis-gen + GEMM. Tile 64(M) x 128(N), BK=32 (= 2 input features * 16),
// 256 threads = 4 waves (2x2), wave tile 32x64 (2x4 frags of 16x16x32 bf16).
// blockIdx.z partitions K-steps; partials atomicAdd'ed into pre-zeroed outp.
template <int NTERMS>
__global__ __launch_bounds__(256) void kan_layer(
    const float* __restrict__ act, const ushort_t* __restrict__ cmh,
    const ushort_t* __restrict__ cml, float* __restrict__ outp,
    int IN, int OUT) {
  const int K = IN * 16;
  __shared__ ushort_t Ah[64 * 40];                       // stride 40 (=20 banks): conflict-ok b128
  __shared__ ushort_t Al[NTERMS == 3 ? 64 * 40 : 1];
  __shared__ ushort_t Bh[128 * 32];                      // XOR-swizzled 8-chunks, no pad
  __shared__ ushort_t Bl[NTERMS == 3 ? 128 * 32 : 1];

  const int tid = threadIdx.x;
  const int lane = tid & 63;
  const int wv = tid >> 6;
  const int wm = wv >> 1, wn = wv & 1;    // 2x2 wave grid
  const int quad = lane >> 4, l15 = lane & 15;
  const int b0 = blockIdx.x * 64;
  const int n0 = blockIdx.y * 128;

  float4v acc[2][4];
#pragma unroll
  for (int a = 0; a < 2; a++)
#pragma unroll
    for (int b = 0; b < 4; b++) acc[a][b] = (float4v)0.0f;

  // basis-gen assignment: unit = (row 0..63, feat 0..1); two threads per unit
  // (hilo 0 -> Ah, hilo 1 -> Al), eval duplicated (cheap VALU).
  const int gunit = tid & 127;
  const int gm = gunit >> 1;
  const int gfeat = gunit & 1;
  const int ghilo = tid >> 7;

  const int nsteps = K / 32;
  const int Z = gridDim.z;
  const int chunk = (nsteps + Z - 1) / Z;
  const int kbeg = blockIdx.z * chunk;
  const int kend = min(kbeg + chunk, nsteps);
  for (int kstep = kbeg; kstep < kend; ++kstep) {
    const int i0 = kstep * 2;
    __syncthreads();   // previous iteration's reads done before overwrite

    // ---- stage B tile (hi/lo): 512 8-chunks/matrix, slot = col8 ^ (row&3) ----
#pragma unroll
    for (int c = 0; c < 2; ++c) {
      int chk = c * 256 + tid;
      int r = chk >> 2;                      // 0..127
      int col8 = chk & 3;
      int slot = col8 ^ (r & 3);
      size_t goff = (size_t)(n0 + r) * K + (size_t)kstep * 32 + col8 * 8;
      *(uint4*)&Bh[r * 32 + slot * 8] = *(const uint4*)&cmh[goff];
      if (NTERMS == 3)
        *(uint4*)&Bl[r * 32 + slot * 8] = *(const uint4*)&cml[goff];
    }

    // ---- generate A tile: 128 x-values -> 4-tap basis, scatter hi or lo ----
    if (NTERMS == 3 || ghilo == 0) {
      float xval = act[(size_t)(b0 + gm) * IN + i0 + gfeat];
      int k0; float w[4];
      bspline_w4(xval, k0, w);
      ushort_t* arow = (ghilo == 0) ? &Ah[gm * 40 + gfeat * 16]
                                    : &Al[gm * 40 + gfeat * 16];
      uint4 z; z.x = z.y = z.z = z.w = 0u;
      ((uint4*)arow)[0] = z; ((uint4*)arow)[1] = z;
      if (ghilo == 0) {
#pragma unroll
        for (int t = 0; t < 4; ++t) arow[k0 + t] = f2bf(w[t]);
      } else {
#pragma unroll
        for (int t = 0; t < 4; ++t) {
          ushort_t h = f2bf(w[t]);
          arow[k0 + t] = f2bf(w[t] - bf2f(h));
        }
      }
    }
    __syncthreads();

    // ---- MFMA: one K=32 depth per kstep ----
    {
      short8 ah[2], al[2], bh[4], bl[4];
#pragma unroll
      for (int mt = 0; mt < 2; ++mt) {
        int off = (wm * 32 + mt * 16 + l15) * 40 + quad * 8;
        ah[mt] = *(const short8*)&Ah[off];
        if (NTERMS == 3) al[mt] = *(const short8*)&Al[off];
      }
#pragma unroll
      for (int nt = 0; nt < 4; ++nt) {
        int n = wn * 64 + nt * 16 + l15;
        int slot = quad ^ (n & 3);
        int off = n * 32 + slot * 8;
        bh[nt] = *(const short8*)&Bh[off];
        if (NTERMS == 3) bl[nt] = *(const short8*)&Bl[off];
      }
#pragma unroll
      for (int mt = 0; mt < 2; ++mt)
#pragma unroll
        for (int nt = 0; nt < 4; ++nt) {
          if (NTERMS == 3) {
            acc[mt][nt] = __builtin_amdgcn_mfma_f32_16x16x32_bf16(al[mt], bh[nt], acc[mt][nt], 0, 0, 0);
            acc[mt][nt] = __builtin_amdgcn_mfma_f32_16x16x32_bf16(ah[mt], bl[nt], acc[mt][nt], 0, 0, 0);
          }
          acc[mt][nt] = __builtin_amdgcn_mfma_f32_16x16x32_bf16(ah[mt], bh[nt], acc[mt][nt], 0, 0, 0);
        }
    }
  }

  // ---- epilogue: C/D layout col=lane&15, row=quad*4+reg; split-K atomics ----
#pragma unroll
  for (int mt = 0; mt < 2; ++mt)
#pragma unroll
    for (int nt = 0; nt < 4; ++nt) {
      int col = n0 + wn * 64 + nt * 16 + l15;
#pragma unroll
      for (int r = 0; r < 4; ++r) {
        int row = b0 + wm * 32 + mt * 16 + quad * 4 + r;
        atomicAdd(&outp[(size_t)row * OUT + col], acc[mt][nt][r]);
      }
    }
}

// KL accumulation + split-bf16 weight conversion in one pass over cm/lv.
__global__ __launch_bounds__(256) void kl_convert(
    const float* __restrict__ cm, const float* __restrict__ lv,
    ushort_t* __restrict__ ch, ushort_t* __restrict__ cl,
    long long n, float* __restrict__ klout) {
  long long i = (long long)blockIdx.x * blockDim.x + threadIdx.x;
  const long long stride = (long long)gridDim.x * blockDim.x;
  float s = 0.0f;
  for (; i < n; i += stride) {
    float c = cm[i], l = lv[i];
    ushort_t h = f2bf(c);
    ch[i] = h;
    cl[i] = f2bf(c - bf2f(h));
    s += 0.5f * (__expf(l) + c * c - 1.0f - l);
  }
#pragma unroll
  for (int o = 32; o > 0; o >>= 1) s += __shfl_down(s, o, 64);
  __shared__ float red[4];
  int wv = threadIdx.x >> 6;
  if ((threadIdx.x & 63) == 0) red[wv] = s;
  __syncthreads();
  if (threadIdx.x == 0)
    atomicAdd(klout, red[0] + red[1] + red[2] + red[3]);
}

extern "C" void kernel_launch(void* const* d_in, const int* in_sizes, int n_in,
                              void* d_out, int out_size, void* d_ws, size_t ws_size,
                              hipStream_t stream) {
  const float* x   = (const float*)d_in[0];
  const float* cm0 = (const float*)d_in[1];
  const float* lv0 = (const float*)d_in[2];
  const float* cm1 = (const float*)d_in[3];
  const float* lv1 = (const float*)d_in[4];
  const float* cm2 = (const float*)d_in[5];
  const float* lv2 = (const float*)d_in[6];

  float* out = (float*)d_out;                       // (8192*256) out + 1 KL
  float* klp = out + (size_t)8192 * 256;

  // ws layout (needs 64 MB): acts 2x16MB, split weights 32MB
  char* ws = (char*)d_ws;
  float*    act1 = (float*)(ws);                               // 8192*512 f32
  float*    act2 = (float*)(ws + ((size_t)16 << 20));          // 8192*512 f32
  ushort_t* c0h  = (ushort_t*)(ws + ((size_t)32 << 20));       // 512*256*16
  ushort_t* c0l  = (ushort_t*)(ws + ((size_t)36 << 20));
  ushort_t* c1h  = (ushort_t*)(ws + ((size_t)40 << 20));       // 512*512*16
  ushort_t* c1l  = (ushort_t*)(ws + ((size_t)48 << 20));
  ushort_t* c2h  = (ushort_t*)(ws + ((size_t)56 << 20));       // 256*512*16
  ushort_t* c2l  = (ushort_t*)(ws + ((size_t)60 << 20));

  // zero split-K accumulation targets (act1+act2 contiguous; d_out incl KL)
  hipMemsetAsync(ws, 0, (size_t)32 << 20, stream);
  hipMemsetAsync(d_out, 0, (size_t)out_size * sizeof(float), stream);

  kl_convert<<<2048, 256, 0, stream>>>(cm0, lv0, c0h, c0l, 512LL * 256 * 16, klp);
  kl_convert<<<2048, 256, 0, stream>>>(cm1, lv1, c1h, c1l, 512LL * 512 * 16, klp);
  kl_convert<<<2048, 256, 0, stream>>>(cm2, lv2, c2h, c2l, 256LL * 512 * 16, klp);

  // 1024 blocks each -> ~4 blocks/CU (LDS 26624 allows 6; regs ~4 waves/SIMD)
  kan_layer<3><<<dim3(128, 4, 2), 256, 0, stream>>>(x,    c0h, c0l, act1, 256, 512);
  kan_layer<3><<<dim3(128, 4, 2), 256, 0, stream>>>(act1, c1h, c1l, act2, 512, 512);
  kan_layer<1><<<dim3(128, 2, 4), 256, 0, stream>>>(act2, c2h, c2l, out,  512, 256);
}

// Round 4
// 538.941 us; speedup vs baseline: 1.3503x; 1.3503x over previous
//
#include <hip/hip_runtime.h>
#include <hip/hip_bf16.h>

// BayesianKAN: 3 layers of  out[b,o] = sum_{i,k} B-spline-basis(x[b,i])[k] * cm[o,i,k]
// == GEMM (M=8192, N=OUT, K=IN*16) with generated A-operand, plus KL scalar.
// R4 numerics: f16 MFMA. L0: 2-term basis-split (ah+al f16, b f16) -- L0 noise is
// amplified ~165x downstream. L1/L2: 1-term f16 (amplification 13x / 1x).
// R4 structure: back to R2's 128x128/BK=64 tile (R3's small tile quadrupled
// barriers/MFMA and regressed). LDS cut via 1-term -> 34816 B -> 4 blocks/CU.
// B staged via global_load_lds width=16 (swizzle folded into per-lane source).

typedef __attribute__((ext_vector_type(8))) _Float16 f16x8;  // 8 f16 in 4 VGPRs
typedef __attribute__((ext_vector_type(4))) float float4v;   // MFMA accumulator
typedef unsigned short ushort_t;

#define GLOBAL_AS __attribute__((address_space(1)))
#define LDS_AS __attribute__((address_space(3)))

__device__ __forceinline__ void async_copy16(const void* g, void* l) {
  __builtin_amdgcn_global_load_lds((const GLOBAL_AS unsigned int*)g,
                                   (LDS_AS unsigned int*)l, 16, 0, 0);
}

__device__ __forceinline__ ushort_t f2h(float f) {
  _Float16 h = (_Float16)f;                 // RTE
  return *(ushort_t*)&h;
}
__device__ __forceinline__ float h2f(ushort_t u) {
  return (float)*(_Float16*)&u;
}

// Cubic B-spline (n_basis=16, clamped uniform knots: 13 cells of width 1/13).
__device__ __forceinline__ void bspline_w4(float x, int& k0, float w[4]) {
  const float XMAX = 1.0f - 1e-6f;
  float xe = fminf(fmaxf(x, 0.0f), XMAX);
  int cell = (int)(xe * 13.0f);
  cell = cell > 12 ? 12 : cell;
  k0 = cell;
  int j = cell + 3;                 // knot span, 3..15
  const float s = 1.0f / 13.0f;
  int cjm2 = max(j - 5, 0);
  int cjm1 = max(j - 4, 0);
  int cj   = j - 3;
  int cj1  = j - 2;
  int cj2  = min(j - 1, 13);
  int cj3  = min(j, 13);
  float tjm2 = cjm2 * s, tjm1 = cjm1 * s, tj = cj * s;
  float tj1 = cj1 * s, tj2 = cj2 * s, tj3 = cj3 * s;
  float left1 = xe - tj, left2 = xe - tjm1, left3 = xe - tjm2;
  float right1 = tj1 - xe, right2 = tj2 - xe, right3 = tj3 - xe;
#define INV3(d) ((d) == 1 ? 13.0f : ((d) == 2 ? 6.5f : (13.0f / 3.0f)))
  float i10 = INV3(cj1 - cj);
  float i20 = INV3(cj1 - cjm1), i21 = INV3(cj2 - cj);
  float i30 = INV3(cj1 - cjm2), i31 = INV3(cj2 - cjm1), i32 = INV3(cj3 - cj);
#undef INV3
  float temp = i10;
  float N0 = right1 * temp;
  float N1 = left1 * temp;
  temp = N0 * i20;
  N0 = right1 * temp;
  float saved = left2 * temp;
  temp = N1 * i21;
  N1 = saved + right2 * temp;
  float N2 = left1 * temp;
  temp = N0 * i30;
  N0 = right1 * temp;
  saved = left3 * temp;
  temp = N1 * i31;
  N1 = saved + right2 * temp;
  saved = left2 * temp;
  temp = N2 * i32;
  N2 = saved + right3 * temp;
  float N3 = left1 * temp;
  w[0] = N0; w[1] = N1; w[2] = N2; w[3] = N3;
}

// Fused basis-gen + GEMM. Tile 128x128, BK=64 (4 feats x 16 basis), 256 thr =
// 4 waves 2x2, wave tile 64x64 (4x4 frags of f32_16x16x32_f16).
// SPLIT_A: A split into f16 hi+lo (2 MFMA/frag-pair). Else 1 MFMA.
// blockIdx.z = split-K; partials atomicAdd into pre-zeroed outp.
template <bool SPLIT_A>
__global__ __launch_bounds__(256) void kan_layer(
    const float* __restrict__ act, const ushort_t* __restrict__ cmh,
    float* __restrict__ outp, int IN, int OUT) {
  const int K = IN * 16;
  __shared__ ushort_t Ah[128 * 72];                  // stride 72: +8 pad, b128-safe
  __shared__ ushort_t Al[SPLIT_A ? 128 * 72 : 1];
  __shared__ ushort_t Bh[128 * 64];                  // chunk slot = col8 ^ (row&7)

  const int tid = threadIdx.x;
  const int lane = tid & 63;
  const int wv = tid >> 6;
  const int wm = wv >> 1, wn = wv & 1;    // 2x2 wave grid
  const int quad = lane >> 4, l15 = lane & 15;
  const int b0 = blockIdx.x * 128;
  const int n0 = blockIdx.y * 128;

  float4v acc[4][4];
#pragma unroll
  for (int a = 0; a < 4; a++)
#pragma unroll
    for (int b = 0; b < 4; b++) acc[a][b] = (float4v)0.0f;

  const int gm = tid >> 1;            // basis-gen: row 0..127
  const int gip = (tid & 1) * 2;      // feat-pair base (0 or 2) of 4 per kstep

  // global_load_lds source mapping: window w covers LDS rows 8w..8w+7; lane l
  // writes LDS byte w*1024 + 16*l, which holds (row = 8w + (l>>3),
  // slot = l&7); source col8 = slot ^ (row&7) = (l&7) ^ (l>>3).
  const int lrow = lane >> 3;
  const int lcol8 = (lane & 7) ^ lrow;

  const int nsteps = K / 64;
  const int Z = gridDim.z;
  const int chunk = nsteps / Z;
  const int kbeg = blockIdx.z * chunk;
  const int kend = min(kbeg + chunk, nsteps);
  for (int kstep = kbeg; kstep < kend; ++kstep) {
    const int i0 = kstep * 4;
    __syncthreads();   // previous iteration's reads done before overwrite

    // ---- stage B tile: 16 windows x 1KB via async global->LDS, width 16 ----
#pragma unroll
    for (int j = 0; j < 4; ++j) {
      int w = wv * 4 + j;
      size_t goff = (size_t)(n0 + w * 8 + lrow) * K + (size_t)kstep * 64 + lcol8 * 8;
      async_copy16(&cmh[goff], &Bh[w * 512]);
    }

    // ---- generate A tile: 512 x-values -> 4-tap basis (f16 hi [+ lo]) ----
    {
      const float2 xv = *(const float2*)&act[(size_t)(b0 + gm) * IN + i0 + gip];
      uint4 z; z.x = z.y = z.z = z.w = 0u;
      ushort_t* arow_h = &Ah[gm * 72 + gip * 16];
      ((uint4*)arow_h)[0] = z; ((uint4*)arow_h)[1] = z;
      ((uint4*)arow_h)[2] = z; ((uint4*)arow_h)[3] = z;
      ushort_t* arow_l = nullptr;
      if (SPLIT_A) {
        arow_l = &Al[gm * 72 + gip * 16];
        ((uint4*)arow_l)[0] = z; ((uint4*)arow_l)[1] = z;
        ((uint4*)arow_l)[2] = z; ((uint4*)arow_l)[3] = z;
      }
#pragma unroll
      for (int e = 0; e < 2; ++e) {
        int k0; float w[4];
        bspline_w4(e == 0 ? xv.x : xv.y, k0, w);
#pragma unroll
        for (int t = 0; t < 4; ++t) {
          ushort_t h = f2h(w[t]);
          arow_h[e * 16 + k0 + t] = h;
          if (SPLIT_A)
            arow_l[e * 16 + k0 + t] = f2h(w[t] - h2f(h));
        }
      }
    }
    __syncthreads();   // also drains the async B loads (vmcnt)

    // ---- MFMA over the two 32-deep halves of BK=64 ----
#pragma unroll
    for (int ks = 0; ks < 2; ++ks) {
      f16x8 ah[4], al[4], bh[4];
#pragma unroll
      for (int mt = 0; mt < 4; ++mt) {
        int off = (wm * 64 + mt * 16 + l15) * 72 + ks * 32 + quad * 8;
        ah[mt] = *(const f16x8*)&Ah[off];
        if (SPLIT_A) al[mt] = *(const f16x8*)&Al[off];
      }
#pragma unroll
      for (int nt = 0; nt < 4; ++nt) {
        int n = wn * 64 + nt * 16 + l15;
        int slot = (ks * 4 + quad) ^ (n & 7);
        bh[nt] = *(const f16x8*)&Bh[n * 64 + slot * 8];
      }
#pragma unroll
      for (int mt = 0; mt < 4; ++mt)
#pragma unroll
        for (int nt = 0; nt < 4; ++nt) {
          if (SPLIT_A)
            acc[mt][nt] = __builtin_amdgcn_mfma_f32_16x16x32_f16(al[mt], bh[nt], acc[mt][nt], 0, 0, 0);
          acc[mt][nt] = __builtin_amdgcn_mfma_f32_16x16x32_f16(ah[mt], bh[nt], acc[mt][nt], 0, 0, 0);
        }
    }
  }

  // ---- epilogue: C/D layout col=lane&15, row=quad*4+reg; split-K atomics ----
#pragma unroll
  for (int mt = 0; mt < 4; ++mt)
#pragma unroll
    for (int nt = 0; nt < 4; ++nt) {
      int col = n0 + wn * 64 + nt * 16 + l15;
#pragma unroll
      for (int r = 0; r < 4; ++r) {
        int row = b0 + wm * 64 + mt * 16 + quad * 4 + r;
        atomicAdd(&outp[(size_t)row * OUT + col], acc[mt][nt][r]);
      }
    }
}

// KL accumulation + f16 weight conversion in one pass over cm/lv.
__global__ __launch_bounds__(256) void kl_convert(
    const float* __restrict__ cm, const float* __restrict__ lv,
    ushort_t* __restrict__ ch, long long n, float* __restrict__ klout) {
  long long i = (long long)blockIdx.x * blockDim.x + threadIdx.x;
  const long long stride = (long long)gridDim.x * blockDim.x;
  float s = 0.0f;
  for (; i < n; i += stride) {
    float c = cm[i], l = lv[i];
    ch[i] = f2h(c);
    s += 0.5f * (__expf(l) + c * c - 1.0f - l);
  }
#pragma unroll
  for (int o = 32; o > 0; o >>= 1) s += __shfl_down(s, o, 64);
  __shared__ float red[4];
  int wv = threadIdx.x >> 6;
  if ((threadIdx.x & 63) == 0) red[wv] = s;
  __syncthreads();
  if (threadIdx.x == 0)
    atomicAdd(klout, red[0] + red[1] + red[2] + red[3]);
}

extern "C" void kernel_launch(void* const* d_in, const int* in_sizes, int n_in,
                              void* d_out, int out_size, void* d_ws, size_t ws_size,
                              hipStream_t stream) {
  const float* x   = (const float*)d_in[0];
  const float* cm0 = (const float*)d_in[1];
  const float* lv0 = (const float*)d_in[2];
  const float* cm1 = (const float*)d_in[3];
  const float* lv1 = (const float*)d_in[4];
  const float* cm2 = (const float*)d_in[5];
  const float* lv2 = (const float*)d_in[6];

  float* out = (float*)d_out;                       // (8192*256) out + 1 KL
  float* klp = out + (size_t)8192 * 256;

  // ws layout (48 MB): acts 2x16MB, f16 weights 16MB
  char* ws = (char*)d_ws;
  float*    act1 = (float*)(ws);                               // 8192*512 f32
  float*    act2 = (float*)(ws + ((size_t)16 << 20));          // 8192*512 f32
  ushort_t* c0h  = (ushort_t*)(ws + ((size_t)32 << 20));       // 512*256*16 f16
  ushort_t* c1h  = (ushort_t*)(ws + ((size_t)36 << 20));       // 512*512*16 f16
  ushort_t* c2h  = (ushort_t*)(ws + ((size_t)44 << 20));       // 256*512*16 f16

  // zero split-K accumulation targets (act1+act2 contiguous; d_out incl KL)
  hipMemsetAsync(ws, 0, (size_t)32 << 20, stream);
  hipMemsetAsync(d_out, 0, (size_t)out_size * sizeof(float), stream);

  kl_convert<<<2048, 256, 0, stream>>>(cm0, lv0, c0h, 512LL * 256 * 16, klp);
  kl_convert<<<2048, 256, 0, stream>>>(cm1, lv1, c1h, 512LL * 512 * 16, klp);
  kl_convert<<<2048, 256, 0, stream>>>(cm2, lv2, c2h, 256LL * 512 * 16, klp);

  // 1024 blocks/layer; LDS: L0 53248 B (3 blk/CU), L1/L2 34816 B (4 blk/CU)
  kan_layer<true ><<<dim3(64, 4, 4), 256, 0, stream>>>(x,    c0h, act1, 256, 512);
  kan_layer<false><<<dim3(64, 4, 4), 256, 0, stream>>>(act1, c1h, act2, 512, 512);
  kan_layer<false><<<dim3(64, 2, 8), 256, 0, stream>>>(act2, c2h, out,  512, 256);
}

// Round 5
// 486.860 us; speedup vs baseline: 1.4948x; 1.1070x over previous
//
#include <hip/hip_runtime.h>
#include <hip/hip_bf16.h>

// BayesianKAN: 3 layers of  out[b,o] = sum_{i,k} B-spline-basis(x[b,i])[k] * cm[o,i,k]
// == GEMM (M=8192, N=OUT, K=IN*16) with generated A-operand, plus KL scalar.
// Numerics (validated R4): f16 MFMA; L0 2-term A-split (downstream gain ~165x),
// L1/L2 1-term. Reported absmax 0.353 = KL fp32-atomic ordering vs 9.6e4 thr.
// R5: B never touches LDS. kl_convert pre-swizzles weights into MFMA-fragment-
// contiguous order Bsw[n/16][k/8][n%16][8] so each B frag is one coalesced 1KB
// global_load_dwordx4 into VGPRs (L3-resident), issued at loop top. LDS keeps
// only the generated A tile (18KB) -> halves LDS-pipe traffic per kstep, which
// R4 counters showed to be the ceiling (MfmaUtil 19% ~= MFMA/LDS-pipe ratio).

typedef __attribute__((ext_vector_type(8))) _Float16 f16x8;  // 8 f16 in 4 VGPRs
typedef __attribute__((ext_vector_type(4))) float float4v;   // MFMA accumulator
typedef unsigned short ushort_t;

__device__ __forceinline__ ushort_t f2h(float f) {
  _Float16 h = (_Float16)f;                 // RTE
  return *(ushort_t*)&h;
}
__device__ __forceinline__ float h2f(ushort_t u) {
  return (float)*(_Float16*)&u;
}

// Cubic B-spline (n_basis=16, clamped uniform knots: 13 cells of width 1/13).
__device__ __forceinline__ void bspline_w4(float x, int& k0, float w[4]) {
  const float XMAX = 1.0f - 1e-6f;
  float xe = fminf(fmaxf(x, 0.0f), XMAX);
  int cell = (int)(xe * 13.0f);
  cell = cell > 12 ? 12 : cell;
  k0 = cell;
  int j = cell + 3;                 // knot span, 3..15
  const float s = 1.0f / 13.0f;
  int cjm2 = max(j - 5, 0);
  int cjm1 = max(j - 4, 0);
  int cj   = j - 3;
  int cj1  = j - 2;
  int cj2  = min(j - 1, 13);
  int cj3  = min(j, 13);
  float tjm1 = cjm1 * s, tj = cj * s;
  float tjm2 = cjm2 * s;
  float tj1 = cj1 * s, tj2 = cj2 * s, tj3 = cj3 * s;
  float left1 = xe - tj, left2 = xe - tjm1, left3 = xe - tjm2;
  float right1 = tj1 - xe, right2 = tj2 - xe, right3 = tj3 - xe;
#define INV3(d) ((d) == 1 ? 13.0f : ((d) == 2 ? 6.5f : (13.0f / 3.0f)))
  float i10 = INV3(cj1 - cj);
  float i20 = INV3(cj1 - cjm1), i21 = INV3(cj2 - cj);
  float i30 = INV3(cj1 - cjm2), i31 = INV3(cj2 - cjm1), i32 = INV3(cj3 - cj);
#undef INV3
  float temp = i10;
  float N0 = right1 * temp;
  float N1 = left1 * temp;
  temp = N0 * i20;
  N0 = right1 * temp;
  float saved = left2 * temp;
  temp = N1 * i21;
  N1 = saved + right2 * temp;
  float N2 = left1 * temp;
  temp = N0 * i30;
  N0 = right1 * temp;
  saved = left3 * temp;
  temp = N1 * i31;
  N1 = saved + right2 * temp;
  saved = left2 * temp;
  temp = N2 * i32;
  N2 = saved + right3 * temp;
  float N3 = left1 * temp;
  w[0] = N0; w[1] = N1; w[2] = N2; w[3] = N3;
}

// Fused basis-gen + GEMM. Tile 128x128, BK=64 (4 feats x 16 basis), 256 thr =
// 4 waves 2x2, wave tile 64x64 (4x4 frags of f32_16x16x32_f16).
// A (generated) staged via LDS; B read fragment-direct global->VGPR from Bsw.
// blockIdx.z = split-K; partials atomicAdd into pre-zeroed outp.
template <bool SPLIT_A>
__global__ __launch_bounds__(256, 2) void kan_layer(
    const float* __restrict__ act, const ushort_t* __restrict__ Bsw,
    float* __restrict__ outp, int IN, int OUT) {
  const int K = IN * 16;
  const int KC = K >> 3;                             // k-chunks of 8
  __shared__ ushort_t Ah[128 * 72];                  // stride 72: +8 pad
  __shared__ ushort_t Al[SPLIT_A ? 128 * 72 : 1];

  const int tid = threadIdx.x;
  const int lane = tid & 63;
  const int wv = tid >> 6;
  const int wm = wv >> 1, wn = wv & 1;    // 2x2 wave grid
  const int quad = lane >> 4, l15 = lane & 15;
  const int b0 = blockIdx.x * 128;
  const int n0 = blockIdx.y * 128;
  const int tbase = (n0 >> 4) + wn * 4;   // B row-tile base for this wave

  float4v acc[4][4];
#pragma unroll
  for (int a = 0; a < 4; a++)
#pragma unroll
    for (int b = 0; b < 4; b++) acc[a][b] = (float4v)0.0f;

  const int gm = tid >> 1;            // basis-gen: row 0..127
  const int gip = (tid & 1) * 2;      // feat-pair base (0 or 2) of 4 per kstep

  const int nsteps = K / 64;
  const int chunk = nsteps / gridDim.z;
  const int kbeg = blockIdx.z * chunk;
  const int kend = kbeg + chunk;
  for (int kstep = kbeg; kstep < kend; ++kstep) {
    const int i0 = kstep * 4;

    // ---- issue activation load + all 8 B-fragment loads (global->VGPR) ----
    const float2 xv = *(const float2*)&act[(size_t)(b0 + gm) * IN + i0 + gip];
    f16x8 bfrag[2][4];
#pragma unroll
    for (int ks = 0; ks < 2; ++ks)
#pragma unroll
      for (int nt = 0; nt < 4; ++nt) {
        size_t eoff = (((size_t)(tbase + nt)) * KC + kstep * 8 + ks * 4) * 128
                      + lane * 8;
        bfrag[ks][nt] = *(const f16x8*)&Bsw[eoff];
      }

    // ---- evaluate splines in registers (VALU only) ----
    int k0a, k0b; float wa[4], wb[4];
    bspline_w4(xv.x, k0a, wa);
    bspline_w4(xv.y, k0b, wb);

    __syncthreads();   // previous iteration's A-frag reads complete

    // ---- write A tile: zero two 16-f16 segments, scatter 4 taps each ----
    {
      uint4 z; z.x = z.y = z.z = z.w = 0u;
      ushort_t* arow_h = &Ah[gm * 72 + gip * 16];
      ((uint4*)arow_h)[0] = z; ((uint4*)arow_h)[1] = z;
      ((uint4*)arow_h)[2] = z; ((uint4*)arow_h)[3] = z;
#pragma unroll
      for (int t = 0; t < 4; ++t) {
        arow_h[k0a + t] = f2h(wa[t]);
        arow_h[16 + k0b + t] = f2h(wb[t]);
      }
      if (SPLIT_A) {
        ushort_t* arow_l = &Al[gm * 72 + gip * 16];
        ((uint4*)arow_l)[0] = z; ((uint4*)arow_l)[1] = z;
        ((uint4*)arow_l)[2] = z; ((uint4*)arow_l)[3] = z;
#pragma unroll
        for (int t = 0; t < 4; ++t) {
          arow_l[k0a + t] = f2h(wa[t] - h2f(f2h(wa[t])));
          arow_l[16 + k0b + t] = f2h(wb[t] - h2f(f2h(wb[t])));
        }
      }
    }
    __syncthreads();   // A tile ready

    // ---- MFMA over the two 32-deep halves of BK=64 ----
#pragma unroll
    for (int ks = 0; ks < 2; ++ks) {
      f16x8 ah[4], al[4];
#pragma unroll
      for (int mt = 0; mt < 4; ++mt) {
        int off = (wm * 64 + mt * 16 + l15) * 72 + ks * 32 + quad * 8;
        ah[mt] = *(const f16x8*)&Ah[off];
        if (SPLIT_A) al[mt] = *(const f16x8*)&Al[off];
      }
#pragma unroll
      for (int mt = 0; mt < 4; ++mt)
#pragma unroll
        for (int nt = 0; nt < 4; ++nt) {
          if (SPLIT_A)
            acc[mt][nt] = __builtin_amdgcn_mfma_f32_16x16x32_f16(al[mt], bfrag[ks][nt], acc[mt][nt], 0, 0, 0);
          acc[mt][nt] = __builtin_amdgcn_mfma_f32_16x16x32_f16(ah[mt], bfrag[ks][nt], acc[mt][nt], 0, 0, 0);
        }
    }
  }

  // ---- epilogue: C/D layout col=lane&15, row=quad*4+reg; split-K atomics ----
#pragma unroll
  for (int mt = 0; mt < 4; ++mt)
#pragma unroll
    for (int nt = 0; nt < 4; ++nt) {
      int col = n0 + wn * 64 + nt * 16 + l15;
#pragma unroll
      for (int r = 0; r < 4; ++r) {
        int row = b0 + wm * 64 + mt * 16 + quad * 4 + r;
        atomicAdd(&outp[(size_t)row * OUT + col], acc[mt][nt][r]);
      }
    }
}

// KL accumulation + f16 conversion + fragment-order swizzle, one pass over cm/lv.
// Group = 8 consecutive k of one output row o: dest Bsw[o/16][k/8][o%16][8].
__global__ __launch_bounds__(256) void kl_convert(
    const float* __restrict__ cm, const float* __restrict__ lv,
    ushort_t* __restrict__ bsw, int G /* = IN*2 groups per row */,
    long long ngroups, float* __restrict__ klout) {
  long long i = (long long)blockIdx.x * blockDim.x + threadIdx.x;
  const long long stride = (long long)gridDim.x * blockDim.x;
  float s = 0.0f;
  for (; i < ngroups; i += stride) {
    int o = (int)(i / G);
    int kc = (int)(i - (long long)o * G);
    const float* cp = &cm[i * 8];
    const float* lp = &lv[i * 8];
    unsigned pk[4];
#pragma unroll
    for (int t = 0; t < 4; ++t) {
      float c0 = cp[2 * t], c1 = cp[2 * t + 1];
      float l0 = lp[2 * t], l1 = lp[2 * t + 1];
      pk[t] = (unsigned)f2h(c0) | ((unsigned)f2h(c1) << 16);
      s += 0.5f * (__expf(l0) + c0 * c0 - 1.0f - l0);
      s += 0.5f * (__expf(l1) + c1 * c1 - 1.0f - l1);
    }
    uint4 v; v.x = pk[0]; v.y = pk[1]; v.z = pk[2]; v.w = pk[3];
    size_t doff = (((size_t)(o >> 4) * G + kc) * 16 + (o & 15)) * 8;
    *(uint4*)&bsw[doff] = v;
  }
#pragma unroll
  for (int off = 32; off > 0; off >>= 1) s += __shfl_down(s, off, 64);
  __shared__ float red[4];
  int wv = threadIdx.x >> 6;
  if ((threadIdx.x & 63) == 0) red[wv] = s;
  __syncthreads();
  if (threadIdx.x == 0)
    atomicAdd(klout, red[0] + red[1] + red[2] + red[3]);
}

extern "C" void kernel_launch(void* const* d_in, const int* in_sizes, int n_in,
                              void* d_out, int out_size, void* d_ws, size_t ws_size,
                              hipStream_t stream) {
  const float* x   = (const float*)d_in[0];
  const float* cm0 = (const float*)d_in[1];
  const float* lv0 = (const float*)d_in[2];
  const float* cm1 = (const float*)d_in[3];
  const float* lv1 = (const float*)d_in[4];
  const float* cm2 = (const float*)d_in[5];
  const float* lv2 = (const float*)d_in[6];

  float* out = (float*)d_out;                       // (8192*256) out + 1 KL
  float* klp = out + (size_t)8192 * 256;

  // ws layout (48 MB): acts 2x16MB, swizzled f16 weights 16MB
  char* ws = (char*)d_ws;
  float*    act1 = (float*)(ws);                               // 8192*512 f32
  float*    act2 = (float*)(ws + ((size_t)16 << 20));          // 8192*512 f32
  ushort_t* b0sw = (ushort_t*)(ws + ((size_t)32 << 20));       // 512*256*16 f16
  ushort_t* b1sw = (ushort_t*)(ws + ((size_t)36 << 20));       // 512*512*16 f16
  ushort_t* b2sw = (ushort_t*)(ws + ((size_t)44 << 20));       // 256*512*16 f16

  // zero split-K accumulation targets (act1+act2 contiguous; d_out incl KL)
  hipMemsetAsync(ws, 0, (size_t)32 << 20, stream);
  hipMemsetAsync(d_out, 0, (size_t)out_size * sizeof(float), stream);

  kl_convert<<<2048, 256, 0, stream>>>(cm0, lv0, b0sw, 256 * 2, 512LL * 256 * 2, klp);
  kl_convert<<<2048, 256, 0, stream>>>(cm1, lv1, b1sw, 512 * 2, 512LL * 512 * 2, klp);
  kl_convert<<<2048, 256, 0, stream>>>(cm2, lv2, b2sw, 512 * 2, 256LL * 512 * 2, klp);

  // 1024 blocks/layer; LDS: L0 36864 B, L1/L2 18432 B
  kan_layer<true ><<<dim3(64, 4, 4), 256, 0, stream>>>(x,    b0sw, act1, 256, 512);
  kan_layer<false><<<dim3(64, 4, 4), 256, 0, stream>>>(act1, b1sw, act2, 512, 512);
  kan_layer<false><<<dim3(64, 2, 8), 256, 0, stream>>>(act2, b2sw, out,  512, 256);
}